// Round 1
// baseline (1653.139 us; speedup 1.0000x reference)
//
#include <hip/hip_runtime.h>

#define N_NODESC 50000
#define N_EDGESC 600000
#define HID 128
#define LAYERS 3
#define N_GRAPHSC 16
#define OUT_DIM 14
#define GEN_EPS 1e-7f
#define BN_EPS 1e-5f

// ---------------- CSR build ----------------
__global__ void k_count(const int* __restrict__ dst, int* __restrict__ deg) {
    int i = blockIdx.x * blockDim.x + threadIdx.x;
    if (i < N_EDGESC) atomicAdd(&deg[dst[i]], 1);
}

__global__ void k_scan(const int* __restrict__ deg, int* __restrict__ row_ptr,
                       int* __restrict__ cursor) {
    __shared__ int part[1024];
    int tid = threadIdx.x;
    const int per = (N_NODESC + 1023) / 1024;  // 49
    int start = tid * per;
    int end = min(start + per, N_NODESC);
    int s = 0;
    for (int i = start; i < end; i++) s += deg[i];
    part[tid] = s;
    __syncthreads();
    for (int off = 1; off < 1024; off <<= 1) {
        int v = part[tid];
        int add = (tid >= off) ? part[tid - off] : 0;
        __syncthreads();
        part[tid] = v + add;
        __syncthreads();
    }
    int run = (tid > 0) ? part[tid - 1] : 0;
    for (int i = start; i < end; i++) {
        row_ptr[i] = run; cursor[i] = run; run += deg[i];
    }
    if (tid == 0) row_ptr[N_NODESC] = part[1023];
}

__global__ void k_scatter(const int* __restrict__ dst, int* __restrict__ cursor,
                          int* __restrict__ eid) {
    int i = blockIdx.x * blockDim.x + threadIdx.x;
    if (i < N_EDGESC) {
        int pos = atomicAdd(&cursor[dst[i]], 1);
        eid[pos] = i;
    }
}

// ---------------- node embedding ----------------
__global__ void k_embed(const int* __restrict__ f0, const int* __restrict__ f1,
                        const float4* __restrict__ W0, const float4* __restrict__ W1,
                        float4* __restrict__ hv4) {
    int i = blockIdx.x * blockDim.x + threadIdx.x;
    if (i >= N_NODESC * (HID / 4)) return;
    int v = i >> 5, c4 = i & 31;
    float4 a = W0[f0[v] * 32 + c4];
    float4 b = W1[f1[v] * 32 + c4];
    hv4[i] = make_float4(a.x + b.x, a.y + b.y, a.z + b.z, a.w + b.w);
}

// ---------------- BatchNorm ----------------
__global__ void k_bn_stats(const float* __restrict__ hv, float* __restrict__ gsum,
                           float* __restrict__ gsumsq) {
    int tid = threadIdx.x;
    int c = tid & 127, rh = tid >> 7;
    float s = 0.f, s2 = 0.f;
    for (int r = blockIdx.x * 2 + rh; r < N_NODESC; r += gridDim.x * 2) {
        float v = hv[(size_t)r * HID + c];
        s += v; s2 += v * v;
    }
    __shared__ float sh[256];
    sh[tid] = s;
    __syncthreads();
    if (tid < 128) atomicAdd(&gsum[c], sh[tid] + sh[tid + 128]);
    __syncthreads();
    sh[tid] = s2;
    __syncthreads();
    if (tid < 128) atomicAdd(&gsumsq[c], sh[tid] + sh[tid + 128]);
}

__global__ void k_bn_fin(const float* __restrict__ gsum, const float* __restrict__ gsumsq,
                         const float* __restrict__ gamma, const float* __restrict__ betab,
                         float* __restrict__ scale, float* __restrict__ shift) {
    int c = threadIdx.x;
    const float invN = 1.f / (float)N_NODESC;
    float mu = gsum[c] * invN;
    float var = gsumsq[c] * invN - mu * mu;
    float rstd = rsqrtf(var + BN_EPS);
    float sc = gamma[c] * rstd;
    scale[c] = sc;
    shift[c] = betab[c] - mu * sc;
}

__global__ void k_hv1(const float4* __restrict__ hv4, const float4* __restrict__ sc4,
                      const float4* __restrict__ sh4, float4* __restrict__ hv14) {
    int i = blockIdx.x * blockDim.x + threadIdx.x;
    if (i >= N_NODESC * (HID / 4)) return;
    int c4 = i & 31;
    float4 v = hv4[i], s = sc4[c4], sh = sh4[c4];
    float4 o;
    o.x = fmaxf(fmaf(v.x, s.x, sh.x), 0.f);
    o.y = fmaxf(fmaf(v.y, s.y, sh.y), 0.f);
    o.z = fmaxf(fmaf(v.z, s.z, sh.z), 0.f);
    o.w = fmaxf(fmaf(v.w, s.w, sh.w), 0.f);
    hv14[i] = o;
}

// ---------------- GENConv aggregation: one wave per node ----------------
// agg[v][c] = sum_e m*exp(beta*m) / sum_e exp(beta*m); x = hv1 + agg
__global__ __launch_bounds__(256) void k_agg(
    const float* __restrict__ hv1, const int* __restrict__ row_ptr,
    const int* __restrict__ csr_eid, const int* __restrict__ edge_src,
    const int* __restrict__ ef0, const int* __restrict__ ef1,
    const float* __restrict__ e0t, const float* __restrict__ e1t,
    const float* __restrict__ beta_p, float* __restrict__ x) {
    int wave = threadIdx.x >> 6;
    int lane = threadIdx.x & 63;
    int v = blockIdx.x * 4 + wave;
    if (v >= N_NODESC) return;
    float beta = *beta_p;
    int c = lane * 2;
    float2 h1 = *(const float2*)(hv1 + (size_t)v * HID + c);
    float n0 = 0.f, n1 = 0.f, d0 = 0.f, d1 = 0.f;
    int p0 = row_ptr[v], p1 = row_ptr[v + 1];
    for (int p = p0; p < p1; p++) {
        int eid = csr_eid[p];
        int src = edge_src[eid];
        float2 h = *(const float2*)(hv1 + (size_t)src * HID + c);
        float2 a = *(const float2*)(e0t + ef0[eid] * HID + c);
        float2 b = *(const float2*)(e1t + ef1[eid] * HID + c);
        float m0 = fmaxf(h.x + a.x + b.x, 0.f) + GEN_EPS;
        float m1 = fmaxf(h.y + a.y + b.y, 0.f) + GEN_EPS;
        float w0 = __expf(beta * m0);
        float w1 = __expf(beta * m1);
        d0 += w0; d1 += w1;
        n0 += m0 * w0; n1 += m1 * w1;
    }
    float2 o;
    o.x = h1.x + ((p1 > p0) ? n0 / d0 : 0.f);
    o.y = h1.y + ((p1 > p0) ? n1 / d1 : 0.f);
    *(float2*)(x + (size_t)v * HID + c) = o;
}

// ---------------- MLP GEMM + bias + skip (in-place into hv) ----------------
// hv[v][c] = x[v][:] dot W[:][c] + b[c] + hv[v][c]
// tile: 32 rows x 64 cols per block; thread = 2 rows x 4 cols
__global__ __launch_bounds__(256) void k_gemm(const float* __restrict__ x,
                                              const float* __restrict__ W,
                                              const float* __restrict__ b,
                                              float* __restrict__ hv) {
    __shared__ float Ws[HID * 64];     // [k][c], stride 64 (conflict-free)
    __shared__ float xs[32 * 129];     // [r][k], stride 129 (pad breaks 128-stride)
    int tid = threadIdx.x;
    int v0 = blockIdx.x * 32;
    int cb = blockIdx.y * 64;
    for (int i = tid; i < HID * 64; i += 256) {
        int k = i >> 6, c = i & 63;
        Ws[i] = W[k * HID + cb + c];
    }
    for (int i = tid; i < 32 * HID; i += 256) {
        int r = i >> 7, k = i & 127;
        int v = v0 + r;
        xs[r * 129 + k] = (v < N_NODESC) ? x[(size_t)v * HID + k] : 0.f;
    }
    __syncthreads();
    int tx = tid & 15, ty = tid >> 4;
    int c0 = tx * 4, r0 = ty * 2;
    float acc[2][4];
#pragma unroll
    for (int i = 0; i < 2; i++)
#pragma unroll
        for (int j = 0; j < 4; j++) acc[i][j] = 0.f;
    for (int k = 0; k < HID; k++) {
        float4 wv = *(const float4*)&Ws[k * 64 + c0];
#pragma unroll
        for (int i = 0; i < 2; i++) {
            float xv = xs[(r0 + i) * 129 + k];
            acc[i][0] = fmaf(xv, wv.x, acc[i][0]);
            acc[i][1] = fmaf(xv, wv.y, acc[i][1]);
            acc[i][2] = fmaf(xv, wv.z, acc[i][2]);
            acc[i][3] = fmaf(xv, wv.w, acc[i][3]);
        }
    }
#pragma unroll
    for (int i = 0; i < 2; i++) {
        int v = v0 + r0 + i;
        if (v < N_NODESC) {
#pragma unroll
            for (int j = 0; j < 4; j++) {
                int c = cb + c0 + j;
                size_t idx = (size_t)v * HID + c;
                hv[idx] = acc[i][j] + b[c] + hv[idx];
            }
        }
    }
}

// ---------------- pooling + output ----------------
__global__ void k_cnt(const int* __restrict__ gids, float* __restrict__ cnt) {
    int i = blockIdx.x * blockDim.x + threadIdx.x;
    if (i < N_NODESC) atomicAdd(&cnt[gids[i]], 1.f);
}

__global__ void k_pool(const float* __restrict__ hv, const int* __restrict__ gids,
                       float* __restrict__ hg) {
    int tid = threadIdx.x;
    int c = tid & 127, rh = tid >> 7;
    int start = blockIdx.x * 512;
    int end = min(start + 512, N_NODESC);
    float acc = 0.f;
    int gp = -1;
    for (int r = start + rh; r < end; r += 2) {
        int g = gids[r];
        if (g != gp) {
            if (gp >= 0) atomicAdd(&hg[gp * HID + c], acc);
            acc = 0.f; gp = g;
        }
        acc += hv[(size_t)r * HID + c];
    }
    if (gp >= 0) atomicAdd(&hg[gp * HID + c], acc);
}

__global__ void k_out(const float* __restrict__ hg, const float* __restrict__ cnt,
                      const float* __restrict__ Wo, const float* __restrict__ bo,
                      float* __restrict__ out) {
    int tid = threadIdx.x;
    if (tid >= N_GRAPHSC * OUT_DIM) return;
    int g = tid / OUT_DIM, o = tid % OUT_DIM;
    float inv = 1.f / cnt[g];
    float acc = bo[o];
    for (int k = 0; k < HID; k++)
        acc += hg[g * HID + k] * inv * Wo[k * OUT_DIM + o];
    out[tid] = acc;
}

extern "C" void kernel_launch(void* const* d_in, const int* in_sizes, int n_in,
                              void* d_out, int out_size, void* d_ws, size_t ws_size,
                              hipStream_t stream) {
    const int* node_feat0 = (const int*)d_in[0];
    const int* node_feat1 = (const int*)d_in[1];
    const int* edge_feat0 = (const int*)d_in[2];
    const int* edge_feat1 = (const int*)d_in[3];
    const int* edge_src   = (const int*)d_in[4];
    const int* edge_dst   = (const int*)d_in[5];
    const int* graph_ids  = (const int*)d_in[6];
    // d_in[7] = num_graphs scalar (known: 16)
    const float* W_node0   = (const float*)d_in[8];
    const float* W_node1   = (const float*)d_in[9];
    const float* edge_emb0 = (const float*)d_in[10];
    const float* edge_emb1 = (const float*)d_in[11];
    const float* beta      = (const float*)d_in[12];
    const float* mlp_W     = (const float*)d_in[13];
    const float* mlp_b     = (const float*)d_in[14];
    const float* bn_gamma  = (const float*)d_in[15];
    const float* bn_beta   = (const float*)d_in[16];
    const float* W_out     = (const float*)d_in[17];
    const float* b_out     = (const float*)d_in[18];
    float* out = (float*)d_out;

    char* ws = (char*)d_ws;
    size_t off = 0;
    auto alloc = [&](size_t bytes) -> void* {
        void* p = ws + off;
        off += (bytes + 255) & ~(size_t)255;
        return p;
    };
    float* hv     = (float*)alloc((size_t)N_NODESC * HID * 4);
    float* hv1    = (float*)alloc((size_t)N_NODESC * HID * 4);
    float* xbuf   = (float*)alloc((size_t)N_NODESC * HID * 4);
    float* gsum   = (float*)alloc(2 * HID * 4);   // gsum + gsumsq contiguous
    float* gsumsq = gsum + HID;
    float* scale  = (float*)alloc(HID * 4);
    float* shift  = (float*)alloc(HID * 4);
    float* hg     = (float*)alloc((N_GRAPHSC * HID + N_GRAPHSC) * 4);  // sums + counts
    float* cntf   = hg + N_GRAPHSC * HID;
    int* row_ptr  = (int*)alloc((N_NODESC + 1) * 4);
    int* cursor   = (int*)alloc(N_NODESC * 4);
    int* deg      = (int*)alloc(N_NODESC * 4);
    int* csr_eid  = (int*)alloc((size_t)N_EDGESC * 4);

    // ---- CSR build (edge_dst is layer-invariant) ----
    hipMemsetAsync(deg, 0, N_NODESC * 4, stream);
    k_count<<<(N_EDGESC + 255) / 256, 256, 0, stream>>>(edge_dst, deg);
    k_scan<<<1, 1024, 0, stream>>>(deg, row_ptr, cursor);
    k_scatter<<<(N_EDGESC + 255) / 256, 256, 0, stream>>>(edge_dst, cursor, csr_eid);

    // ---- node embedding ----
    const int NELEM4 = N_NODESC * (HID / 4);
    k_embed<<<(NELEM4 + 255) / 256, 256, 0, stream>>>(
        node_feat0, node_feat1, (const float4*)W_node0, (const float4*)W_node1,
        (float4*)hv);

    // ---- layers ----
    for (int l = 0; l < LAYERS; l++) {
        hipMemsetAsync(gsum, 0, 2 * HID * 4, stream);
        k_bn_stats<<<200, 256, 0, stream>>>(hv, gsum, gsumsq);
        k_bn_fin<<<1, 128, 0, stream>>>(gsum, gsumsq, bn_gamma + l * HID,
                                        bn_beta + l * HID, scale, shift);
        k_hv1<<<(NELEM4 + 255) / 256, 256, 0, stream>>>(
            (const float4*)hv, (const float4*)scale, (const float4*)shift,
            (float4*)hv1);
        k_agg<<<(N_NODESC + 3) / 4, 256, 0, stream>>>(
            hv1, row_ptr, csr_eid, edge_src, edge_feat0, edge_feat1,
            edge_emb0 + (size_t)l * 6 * HID, edge_emb1 + (size_t)l * 3 * HID,
            beta + l, xbuf);
        dim3 ggrid((N_NODESC + 31) / 32, 2);
        k_gemm<<<ggrid, 256, 0, stream>>>(xbuf, mlp_W + (size_t)l * HID * HID,
                                          mlp_b + l * HID, hv);
    }

    // ---- pooling + output ----
    hipMemsetAsync(hg, 0, (N_GRAPHSC * HID + N_GRAPHSC) * 4, stream);
    k_cnt<<<(N_NODESC + 255) / 256, 256, 0, stream>>>(graph_ids, cntf);
    k_pool<<<(N_NODESC + 511) / 512, 256, 0, stream>>>(hv, graph_ids, hg);
    k_out<<<1, 256, 0, stream>>>(hg, cntf, W_out, b_out, out);
}

// Round 2
// 901.692 us; speedup vs baseline: 1.8334x; 1.8334x over previous
//
#include <hip/hip_runtime.h>

#define N_NODESC 50000
#define N_EDGESC 600000
#define HID 128
#define LAYERS 3
#define N_GRAPHSC 16
#define OUT_DIM 14
#define GEN_EPS 1e-7f
#define BN_EPS 1e-5f

// ---------------- CSR build ----------------
__global__ void k_count(const int* __restrict__ dst, int* __restrict__ deg) {
    int i = blockIdx.x * blockDim.x + threadIdx.x;
    if (i < N_EDGESC) atomicAdd(&deg[dst[i]], 1);
}

__global__ void k_scan(const int* __restrict__ deg, int* __restrict__ row_ptr,
                       int* __restrict__ cursor) {
    __shared__ int part[1024];
    int tid = threadIdx.x;
    const int per = (N_NODESC + 1023) / 1024;  // 49
    int start = tid * per;
    int end = min(start + per, N_NODESC);
    int s = 0;
    for (int i = start; i < end; i++) s += deg[i];
    part[tid] = s;
    __syncthreads();
    for (int off = 1; off < 1024; off <<= 1) {
        int v = part[tid];
        int add = (tid >= off) ? part[tid - off] : 0;
        __syncthreads();
        part[tid] = v + add;
        __syncthreads();
    }
    int run = (tid > 0) ? part[tid - 1] : 0;
    for (int i = start; i < end; i++) {
        row_ptr[i] = run; cursor[i] = run; run += deg[i];
    }
    if (tid == 0) row_ptr[N_NODESC] = part[1023];
}

// scatter edges into CSR order, packing (src | f01<<20) into one int
__global__ void k_scatter(const int* __restrict__ dst, const int* __restrict__ src,
                          const int* __restrict__ f0, const int* __restrict__ f1,
                          int* __restrict__ cursor, int* __restrict__ csr_pack) {
    int i = blockIdx.x * blockDim.x + threadIdx.x;
    if (i < N_EDGESC) {
        int pos = atomicAdd(&cursor[dst[i]], 1);
        csr_pack[pos] = src[i] | ((f0[i] * 3 + f1[i]) << 20);
    }
}

// combined edge-embedding table: etab[l][a*3+b][c] = e0[l][a][c] + e1[l][b][c]
__global__ void k_etab(const float* __restrict__ e0, const float* __restrict__ e1,
                       float* __restrict__ etab) {
    int i = blockIdx.x * blockDim.x + threadIdx.x;
    if (i >= LAYERS * 18 * HID) return;
    int c = i & (HID - 1);
    int row = i >> 7;            // l*18 + a*3 + b
    int l = row / 18;
    int ab = row - l * 18;
    int a = ab / 3, b = ab - a * 3;
    etab[i] = e0[(l * 6 + a) * HID + c] + e1[(l * 3 + b) * HID + c];
}

// ---------------- node embedding ----------------
__global__ void k_embed(const int* __restrict__ f0, const int* __restrict__ f1,
                        const float4* __restrict__ W0, const float4* __restrict__ W1,
                        float4* __restrict__ hv4) {
    int i = blockIdx.x * blockDim.x + threadIdx.x;
    if (i >= N_NODESC * (HID / 4)) return;
    int v = i >> 5, c4 = i & 31;
    float4 a = W0[f0[v] * 32 + c4];
    float4 b = W1[f1[v] * 32 + c4];
    hv4[i] = make_float4(a.x + b.x, a.y + b.y, a.z + b.z, a.w + b.w);
}

// ---------------- BatchNorm ----------------
__global__ void k_bn_stats(const float* __restrict__ hv, float* __restrict__ gsum,
                           float* __restrict__ gsumsq) {
    int tid = threadIdx.x;
    int c = tid & 127, rh = tid >> 7;
    float s = 0.f, s2 = 0.f;
    for (int r = blockIdx.x * 2 + rh; r < N_NODESC; r += gridDim.x * 2) {
        float v = hv[(size_t)r * HID + c];
        s += v; s2 += v * v;
    }
    __shared__ float sh[256];
    sh[tid] = s;
    __syncthreads();
    if (tid < 128) atomicAdd(&gsum[c], sh[tid] + sh[tid + 128]);
    __syncthreads();
    sh[tid] = s2;
    __syncthreads();
    if (tid < 128) atomicAdd(&gsumsq[c], sh[tid] + sh[tid + 128]);
}

__global__ void k_bn_fin(const float* __restrict__ gsum, const float* __restrict__ gsumsq,
                         const float* __restrict__ gamma, const float* __restrict__ betab,
                         float* __restrict__ scale, float* __restrict__ shift) {
    int c = threadIdx.x;
    const float invN = 1.f / (float)N_NODESC;
    float mu = gsum[c] * invN;
    float var = gsumsq[c] * invN - mu * mu;
    float rstd = rsqrtf(var + BN_EPS);
    float sc = gamma[c] * rstd;
    scale[c] = sc;
    shift[c] = betab[c] - mu * sc;
}

__global__ void k_hv1(const float4* __restrict__ hv4, const float4* __restrict__ sc4,
                      const float4* __restrict__ sh4, float4* __restrict__ hv14) {
    int i = blockIdx.x * blockDim.x + threadIdx.x;
    if (i >= N_NODESC * (HID / 4)) return;
    int c4 = i & 31;
    float4 v = hv4[i], s = sc4[c4], sh = sh4[c4];
    float4 o;
    o.x = fmaxf(fmaf(v.x, s.x, sh.x), 0.f);
    o.y = fmaxf(fmaf(v.y, s.y, sh.y), 0.f);
    o.z = fmaxf(fmaf(v.z, s.z, sh.z), 0.f);
    o.w = fmaxf(fmaf(v.w, s.w, sh.w), 0.f);
    hv14[i] = o;
}

// ---------------- GENConv aggregation: one wave per node ----------------
// agg[v][c] = sum_e m*exp(beta*m) / sum_e exp(beta*m); x = hv1 + agg
__global__ __launch_bounds__(256) void k_agg(
    const float* __restrict__ hv1, const int* __restrict__ row_ptr,
    const int* __restrict__ csr_pack, const float* __restrict__ etab,
    const float* __restrict__ beta_p, float* __restrict__ x) {
    int wave = threadIdx.x >> 6;
    int lane = threadIdx.x & 63;
    int v = blockIdx.x * 4 + wave;
    if (v >= N_NODESC) return;
    float beta = *beta_p;
    int c = lane * 2;
    float2 h1 = *(const float2*)(hv1 + (size_t)v * HID + c);
    float n0 = 0.f, n1 = 0.f, d0 = 0.f, d1 = 0.f;
    int p0 = row_ptr[v], p1 = row_ptr[v + 1];
    for (int p = p0; p < p1; p++) {
        int pack = csr_pack[p];
        int src = pack & 0xFFFFF;
        int f01 = pack >> 20;
        float2 h = *(const float2*)(hv1 + (size_t)src * HID + c);
        float2 t = *(const float2*)(etab + f01 * HID + c);
        float m0 = fmaxf(h.x + t.x, 0.f) + GEN_EPS;
        float m1 = fmaxf(h.y + t.y, 0.f) + GEN_EPS;
        float w0 = __expf(beta * m0);
        float w1 = __expf(beta * m1);
        d0 += w0; d1 += w1;
        n0 += m0 * w0; n1 += m1 * w1;
    }
    float2 o;
    o.x = h1.x + ((p1 > p0) ? n0 / d0 : 0.f);
    o.y = h1.y + ((p1 > p0) ? n1 / d1 : 0.f);
    *(float2*)(x + (size_t)v * HID + c) = o;
}

// ---------------- MLP GEMM + bias + skip (in-place into hv) ----------------
// hv[v][c] = x[v][:] dot W[:][c] + b[c] + hv[v][c]
// tile: 32 rows x 64 cols per block; thread = 2 rows x 4 cols
__global__ __launch_bounds__(256) void k_gemm(const float* __restrict__ x,
                                              const float* __restrict__ W,
                                              const float* __restrict__ b,
                                              float* __restrict__ hv) {
    __shared__ float Ws[HID * 64];     // [k][c], stride 64 (conflict-free)
    __shared__ float xs[32 * 129];     // [r][k], stride 129 (pad breaks 128-stride)
    int tid = threadIdx.x;
    int v0 = blockIdx.x * 32;
    int cb = blockIdx.y * 64;
    for (int i = tid; i < HID * 64; i += 256) {
        int k = i >> 6, c = i & 63;
        Ws[i] = W[k * HID + cb + c];
    }
    for (int i = tid; i < 32 * HID; i += 256) {
        int r = i >> 7, k = i & 127;
        int v = v0 + r;
        xs[r * 129 + k] = (v < N_NODESC) ? x[(size_t)v * HID + k] : 0.f;
    }
    __syncthreads();
    int tx = tid & 15, ty = tid >> 4;
    int c0 = tx * 4, r0 = ty * 2;
    float acc[2][4];
#pragma unroll
    for (int i = 0; i < 2; i++)
#pragma unroll
        for (int j = 0; j < 4; j++) acc[i][j] = 0.f;
    for (int k = 0; k < HID; k++) {
        float4 wv = *(const float4*)&Ws[k * 64 + c0];
#pragma unroll
        for (int i = 0; i < 2; i++) {
            float xv = xs[(r0 + i) * 129 + k];
            acc[i][0] = fmaf(xv, wv.x, acc[i][0]);
            acc[i][1] = fmaf(xv, wv.y, acc[i][1]);
            acc[i][2] = fmaf(xv, wv.z, acc[i][2]);
            acc[i][3] = fmaf(xv, wv.w, acc[i][3]);
        }
    }
#pragma unroll
    for (int i = 0; i < 2; i++) {
        int v = v0 + r0 + i;
        if (v < N_NODESC) {
#pragma unroll
            for (int j = 0; j < 4; j++) {
                int c = cb + c0 + j;
                size_t idx = (size_t)v * HID + c;
                hv[idx] = acc[i][j] + b[c] + hv[idx];
            }
        }
    }
}

// ---------------- pooling (sums AND counts, run-batched atomics) ----------------
__global__ void k_pool(const float* __restrict__ hv, const int* __restrict__ gids,
                       float* __restrict__ hg, float* __restrict__ cnt) {
    int tid = threadIdx.x;
    int c = tid & 127, rh = tid >> 7;
    int start = blockIdx.x * 512;
    int end = min(start + 512, N_NODESC);
    float acc = 0.f, cacc = 0.f;
    int gp = -1;
    for (int r = start + rh; r < end; r += 2) {
        int g = gids[r];
        if (g != gp) {
            if (gp >= 0) {
                atomicAdd(&hg[gp * HID + c], acc);
                if (c == 0) atomicAdd(&cnt[gp], cacc);
            }
            acc = 0.f; cacc = 0.f; gp = g;
        }
        acc += hv[(size_t)r * HID + c];
        cacc += 1.f;
    }
    if (gp >= 0) {
        atomicAdd(&hg[gp * HID + c], acc);
        if (c == 0) atomicAdd(&cnt[gp], cacc);
    }
}

__global__ void k_out(const float* __restrict__ hg, const float* __restrict__ cnt,
                      const float* __restrict__ Wo, const float* __restrict__ bo,
                      float* __restrict__ out) {
    int tid = threadIdx.x;
    if (tid >= N_GRAPHSC * OUT_DIM) return;
    int g = tid / OUT_DIM, o = tid % OUT_DIM;
    float inv = 1.f / cnt[g];
    float acc = bo[o];
    for (int k = 0; k < HID; k++)
        acc += hg[g * HID + k] * inv * Wo[k * OUT_DIM + o];
    out[tid] = acc;
}

extern "C" void kernel_launch(void* const* d_in, const int* in_sizes, int n_in,
                              void* d_out, int out_size, void* d_ws, size_t ws_size,
                              hipStream_t stream) {
    const int* node_feat0 = (const int*)d_in[0];
    const int* node_feat1 = (const int*)d_in[1];
    const int* edge_feat0 = (const int*)d_in[2];
    const int* edge_feat1 = (const int*)d_in[3];
    const int* edge_src   = (const int*)d_in[4];
    const int* edge_dst   = (const int*)d_in[5];
    const int* graph_ids  = (const int*)d_in[6];
    // d_in[7] = num_graphs scalar (known: 16)
    const float* W_node0   = (const float*)d_in[8];
    const float* W_node1   = (const float*)d_in[9];
    const float* edge_emb0 = (const float*)d_in[10];
    const float* edge_emb1 = (const float*)d_in[11];
    const float* beta      = (const float*)d_in[12];
    const float* mlp_W     = (const float*)d_in[13];
    const float* mlp_b     = (const float*)d_in[14];
    const float* bn_gamma  = (const float*)d_in[15];
    const float* bn_beta   = (const float*)d_in[16];
    const float* W_out     = (const float*)d_in[17];
    const float* b_out     = (const float*)d_in[18];
    float* out = (float*)d_out;

    char* ws = (char*)d_ws;
    size_t off = 0;
    auto alloc = [&](size_t bytes) -> void* {
        void* p = ws + off;
        off += (bytes + 255) & ~(size_t)255;
        return p;
    };
    float* hv     = (float*)alloc((size_t)N_NODESC * HID * 4);
    float* hv1    = (float*)alloc((size_t)N_NODESC * HID * 4);
    float* xbuf   = (float*)alloc((size_t)N_NODESC * HID * 4);
    float* etab   = (float*)alloc(LAYERS * 18 * HID * 4);
    float* gsum   = (float*)alloc(2 * HID * 4);   // gsum + gsumsq contiguous
    float* gsumsq = gsum + HID;
    float* scale  = (float*)alloc(HID * 4);
    float* shift  = (float*)alloc(HID * 4);
    float* hg     = (float*)alloc((N_GRAPHSC * HID + N_GRAPHSC) * 4);  // sums + counts
    float* cntf   = hg + N_GRAPHSC * HID;
    int* row_ptr  = (int*)alloc((N_NODESC + 1) * 4);
    int* cursor   = (int*)alloc(N_NODESC * 4);
    int* deg      = (int*)alloc(N_NODESC * 4);
    int* csr_pack = (int*)alloc((size_t)N_EDGESC * 4);

    // ---- CSR build (edge_dst is layer-invariant) ----
    hipMemsetAsync(deg, 0, N_NODESC * 4, stream);
    k_count<<<(N_EDGESC + 255) / 256, 256, 0, stream>>>(edge_dst, deg);
    k_scan<<<1, 1024, 0, stream>>>(deg, row_ptr, cursor);
    k_scatter<<<(N_EDGESC + 255) / 256, 256, 0, stream>>>(
        edge_dst, edge_src, edge_feat0, edge_feat1, cursor, csr_pack);
    k_etab<<<(LAYERS * 18 * HID + 255) / 256, 256, 0, stream>>>(
        edge_emb0, edge_emb1, etab);

    // ---- node embedding ----
    const int NELEM4 = N_NODESC * (HID / 4);
    k_embed<<<(NELEM4 + 255) / 256, 256, 0, stream>>>(
        node_feat0, node_feat1, (const float4*)W_node0, (const float4*)W_node1,
        (float4*)hv);

    // ---- layers ----
    for (int l = 0; l < LAYERS; l++) {
        hipMemsetAsync(gsum, 0, 2 * HID * 4, stream);
        k_bn_stats<<<200, 256, 0, stream>>>(hv, gsum, gsumsq);
        k_bn_fin<<<1, 128, 0, stream>>>(gsum, gsumsq, bn_gamma + l * HID,
                                        bn_beta + l * HID, scale, shift);
        k_hv1<<<(NELEM4 + 255) / 256, 256, 0, stream>>>(
            (const float4*)hv, (const float4*)scale, (const float4*)shift,
            (float4*)hv1);
        k_agg<<<(N_NODESC + 3) / 4, 256, 0, stream>>>(
            hv1, row_ptr, csr_pack, etab + (size_t)l * 18 * HID, beta + l, xbuf);
        dim3 ggrid((N_NODESC + 31) / 32, 2);
        k_gemm<<<ggrid, 256, 0, stream>>>(xbuf, mlp_W + (size_t)l * HID * HID,
                                          mlp_b + l * HID, hv);
    }

    // ---- pooling + output ----
    hipMemsetAsync(hg, 0, (N_GRAPHSC * HID + N_GRAPHSC) * 4, stream);
    k_pool<<<(N_NODESC + 511) / 512, 256, 0, stream>>>(hv, graph_ids, hg, cntf);
    k_out<<<1, 256, 0, stream>>>(hg, cntf, W_out, b_out, out);
}

// Round 3
// 789.237 us; speedup vs baseline: 2.0946x; 1.1425x over previous
//
#include <hip/hip_runtime.h>

#define N_NODESC 50000
#define N_EDGESC 600000
#define HID 128
#define LAYERS 3
#define N_GRAPHSC 16
#define OUT_DIM 14
#define GEN_EPS 1e-7f
#define BN_EPS 1e-5f
#define SCAN_BLK 196   // ceil(50000/256)

// ---------------- CSR build ----------------
__global__ void k_count(const int* __restrict__ dst, int* __restrict__ deg) {
    int i = blockIdx.x * blockDim.x + threadIdx.x;
    if (i < N_EDGESC) atomicAdd(&deg[dst[i]], 1);
}

// phase 1: per-block (256 nodes) degree sums
__global__ void k_blocksum(const int* __restrict__ deg, int* __restrict__ part) {
    __shared__ int sh[256];
    int t = threadIdx.x;
    int i = blockIdx.x * 256 + t;
    sh[t] = (i < N_NODESC) ? deg[i] : 0;
    __syncthreads();
    for (int off = 128; off > 0; off >>= 1) {
        if (t < off) sh[t] += sh[t + off];
        __syncthreads();
    }
    if (t == 0) part[blockIdx.x] = sh[0];
}

// phase 2: exclusive scan of 196 partials (one tiny block)
__global__ void k_scanpart(const int* __restrict__ part, int* __restrict__ bofs) {
    __shared__ int sh[256];
    int t = threadIdx.x;
    int v = (t < SCAN_BLK) ? part[t] : 0;
    sh[t] = v;
    __syncthreads();
    for (int off = 1; off < 256; off <<= 1) {
        int add = (t >= off) ? sh[t - off] : 0;
        __syncthreads();
        sh[t] += add;
        __syncthreads();
    }
    if (t < SCAN_BLK) bofs[t] = sh[t] - v;  // exclusive
}

// phase 3: per-block local exclusive scan + block offset -> row_ptr, cursor
__global__ void k_rowptr(const int* __restrict__ deg, const int* __restrict__ bofs,
                         int* __restrict__ row_ptr, int* __restrict__ cursor) {
    __shared__ int sh[256];
    int t = threadIdx.x;
    int i = blockIdx.x * 256 + t;
    int d = (i < N_NODESC) ? deg[i] : 0;
    sh[t] = d;
    __syncthreads();
    for (int off = 1; off < 256; off <<= 1) {
        int add = (t >= off) ? sh[t - off] : 0;
        __syncthreads();
        sh[t] += add;
        __syncthreads();
    }
    if (i < N_NODESC) {
        int rp = bofs[blockIdx.x] + sh[t] - d;  // exclusive
        row_ptr[i] = rp;
        cursor[i] = rp;
    }
    if (i == 0) row_ptr[N_NODESC] = N_EDGESC;
}

// scatter edges into CSR order, packing (src | f01<<20) into one int
__global__ void k_scatter(const int* __restrict__ dst, const int* __restrict__ src,
                          const int* __restrict__ f0, const int* __restrict__ f1,
                          int* __restrict__ cursor, int* __restrict__ csr_pack) {
    int i = blockIdx.x * blockDim.x + threadIdx.x;
    if (i < N_EDGESC) {
        int pos = atomicAdd(&cursor[dst[i]], 1);
        csr_pack[pos] = src[i] | ((f0[i] * 3 + f1[i]) << 20);
    }
}

// combined edge-embedding table: etab[l][a*3+b][c] = e0[l][a][c] + e1[l][b][c]
__global__ void k_etab(const float* __restrict__ e0, const float* __restrict__ e1,
                       float* __restrict__ etab) {
    int i = blockIdx.x * blockDim.x + threadIdx.x;
    if (i >= LAYERS * 18 * HID) return;
    int c = i & (HID - 1);
    int row = i >> 7;            // l*18 + a*3 + b
    int l = row / 18;
    int ab = row - l * 18;
    int a = ab / 3, b = ab - a * 3;
    etab[i] = e0[(l * 6 + a) * HID + c] + e1[(l * 3 + b) * HID + c];
}

// ---------------- node embedding ----------------
__global__ void k_embed(const int* __restrict__ f0, const int* __restrict__ f1,
                        const float4* __restrict__ W0, const float4* __restrict__ W1,
                        float4* __restrict__ hv4) {
    int i = blockIdx.x * blockDim.x + threadIdx.x;
    if (i >= N_NODESC * (HID / 4)) return;
    int v = i >> 5, c4 = i & 31;
    float4 a = W0[f0[v] * 32 + c4];
    float4 b = W1[f1[v] * 32 + c4];
    hv4[i] = make_float4(a.x + b.x, a.y + b.y, a.z + b.z, a.w + b.w);
}

// ---------------- BatchNorm ----------------
__global__ void k_bn_stats(const float* __restrict__ hv, float* __restrict__ gsum,
                           float* __restrict__ gsumsq) {
    int tid = threadIdx.x;
    int c = tid & 127, rh = tid >> 7;
    float s = 0.f, s2 = 0.f;
    for (int r = blockIdx.x * 2 + rh; r < N_NODESC; r += gridDim.x * 2) {
        float v = hv[(size_t)r * HID + c];
        s += v; s2 += v * v;
    }
    __shared__ float sh[256];
    sh[tid] = s;
    __syncthreads();
    if (tid < 128) atomicAdd(&gsum[c], sh[tid] + sh[tid + 128]);
    __syncthreads();
    sh[tid] = s2;
    __syncthreads();
    if (tid < 128) atomicAdd(&gsumsq[c], sh[tid] + sh[tid + 128]);
}

// BN apply + ReLU, computing scale/shift inline from stats (broadcast loads)
__global__ void k_hv1(const float4* __restrict__ hv4, const float* __restrict__ gsum,
                      const float* __restrict__ gsumsq, const float* __restrict__ gamma,
                      const float* __restrict__ betab, float4* __restrict__ hv14) {
    int i = blockIdx.x * blockDim.x + threadIdx.x;
    if (i >= N_NODESC * (HID / 4)) return;
    int c4 = i & 31;
    int c = c4 * 4;
    const float invN = 1.f / (float)N_NODESC;
    float4 v = hv4[i];
    float4 o;
#pragma unroll
    for (int j = 0; j < 4; j++) {
        float mu = gsum[c + j] * invN;
        float var = gsumsq[c + j] * invN - mu * mu;
        float sc = gamma[c + j] * rsqrtf(var + BN_EPS);
        float sf = betab[c + j] - mu * sc;
        float val = (&v.x)[j];
        (&o.x)[j] = fmaxf(fmaf(val, sc, sf), 0.f);
    }
    hv14[i] = o;
}

// ---------------- GENConv aggregation: one wave per node ----------------
// agg[v][c] = sum_e m*exp(beta*m) / sum_e exp(beta*m); x = hv1 + agg
__global__ __launch_bounds__(256) void k_agg(
    const float* __restrict__ hv1, const int* __restrict__ row_ptr,
    const int* __restrict__ csr_pack, const float* __restrict__ etab,
    const float* __restrict__ beta_p, float* __restrict__ x) {
    int wave = threadIdx.x >> 6;
    int lane = threadIdx.x & 63;
    int v = blockIdx.x * 4 + wave;
    if (v >= N_NODESC) return;
    float beta = *beta_p;
    int c = lane * 2;
    float2 h1 = *(const float2*)(hv1 + (size_t)v * HID + c);
    float n0 = 0.f, n1 = 0.f, d0 = 0.f, d1 = 0.f;
    int p0 = row_ptr[v], p1 = row_ptr[v + 1];
    for (int p = p0; p < p1; p++) {
        int pack = csr_pack[p];
        int src = pack & 0xFFFFF;
        int f01 = pack >> 20;
        float2 h = *(const float2*)(hv1 + (size_t)src * HID + c);
        float2 t = *(const float2*)(etab + f01 * HID + c);
        float m0 = fmaxf(h.x + t.x, 0.f) + GEN_EPS;
        float m1 = fmaxf(h.y + t.y, 0.f) + GEN_EPS;
        float w0 = __expf(beta * m0);
        float w1 = __expf(beta * m1);
        d0 += w0; d1 += w1;
        n0 += m0 * w0; n1 += m1 * w1;
    }
    float2 o;
    o.x = h1.x + ((p1 > p0) ? n0 / d0 : 0.f);
    o.y = h1.y + ((p1 > p0) ? n1 / d1 : 0.f);
    *(float2*)(x + (size_t)v * HID + c) = o;
}

// ---------------- MLP GEMM + bias + skip (in-place into hv) ----------------
__global__ __launch_bounds__(256) void k_gemm(const float* __restrict__ x,
                                              const float* __restrict__ W,
                                              const float* __restrict__ b,
                                              float* __restrict__ hv) {
    __shared__ float Ws[HID * 64];     // [k][c], stride 64 (conflict-free)
    __shared__ float xs[32 * 129];     // [r][k], pad breaks 128-stride
    int tid = threadIdx.x;
    int v0 = blockIdx.x * 32;
    int cb = blockIdx.y * 64;
    for (int i = tid; i < HID * 64; i += 256) {
        int k = i >> 6, c = i & 63;
        Ws[i] = W[k * HID + cb + c];
    }
    for (int i = tid; i < 32 * HID; i += 256) {
        int r = i >> 7, k = i & 127;
        int v = v0 + r;
        xs[r * 129 + k] = (v < N_NODESC) ? x[(size_t)v * HID + k] : 0.f;
    }
    __syncthreads();
    int tx = tid & 15, ty = tid >> 4;
    int c0 = tx * 4, r0 = ty * 2;
    float acc[2][4];
#pragma unroll
    for (int i = 0; i < 2; i++)
#pragma unroll
        for (int j = 0; j < 4; j++) acc[i][j] = 0.f;
    for (int k = 0; k < HID; k++) {
        float4 wv = *(const float4*)&Ws[k * 64 + c0];
#pragma unroll
        for (int i = 0; i < 2; i++) {
            float xv = xs[(r0 + i) * 129 + k];
            acc[i][0] = fmaf(xv, wv.x, acc[i][0]);
            acc[i][1] = fmaf(xv, wv.y, acc[i][1]);
            acc[i][2] = fmaf(xv, wv.z, acc[i][2]);
            acc[i][3] = fmaf(xv, wv.w, acc[i][3]);
        }
    }
#pragma unroll
    for (int i = 0; i < 2; i++) {
        int v = v0 + r0 + i;
        if (v < N_NODESC) {
#pragma unroll
            for (int j = 0; j < 4; j++) {
                int c = cb + c0 + j;
                size_t idx = (size_t)v * HID + c;
                hv[idx] = acc[i][j] + b[c] + hv[idx];
            }
        }
    }
}

// ---------------- pooling (sums AND counts, run-batched atomics) ----------------
__global__ void k_pool(const float* __restrict__ hv, const int* __restrict__ gids,
                       float* __restrict__ hg, float* __restrict__ cnt) {
    int tid = threadIdx.x;
    int c = tid & 127, rh = tid >> 7;
    int start = blockIdx.x * 512;
    int end = min(start + 512, N_NODESC);
    float acc = 0.f, cacc = 0.f;
    int gp = -1;
    for (int r = start + rh; r < end; r += 2) {
        int g = gids[r];
        if (g != gp) {
            if (gp >= 0) {
                atomicAdd(&hg[gp * HID + c], acc);
                if (c == 0) atomicAdd(&cnt[gp], cacc);
            }
            acc = 0.f; cacc = 0.f; gp = g;
        }
        acc += hv[(size_t)r * HID + c];
        cacc += 1.f;
    }
    if (gp >= 0) {
        atomicAdd(&hg[gp * HID + c], acc);
        if (c == 0) atomicAdd(&cnt[gp], cacc);
    }
}

__global__ void k_out(const float* __restrict__ hg, const float* __restrict__ cnt,
                      const float* __restrict__ Wo, const float* __restrict__ bo,
                      float* __restrict__ out) {
    int tid = threadIdx.x;
    if (tid >= N_GRAPHSC * OUT_DIM) return;
    int g = tid / OUT_DIM, o = tid % OUT_DIM;
    float inv = 1.f / cnt[g];
    float acc = bo[o];
    for (int k = 0; k < HID; k++)
        acc += hg[g * HID + k] * inv * Wo[k * OUT_DIM + o];
    out[tid] = acc;
}

extern "C" void kernel_launch(void* const* d_in, const int* in_sizes, int n_in,
                              void* d_out, int out_size, void* d_ws, size_t ws_size,
                              hipStream_t stream) {
    const int* node_feat0 = (const int*)d_in[0];
    const int* node_feat1 = (const int*)d_in[1];
    const int* edge_feat0 = (const int*)d_in[2];
    const int* edge_feat1 = (const int*)d_in[3];
    const int* edge_src   = (const int*)d_in[4];
    const int* edge_dst   = (const int*)d_in[5];
    const int* graph_ids  = (const int*)d_in[6];
    const float* W_node0   = (const float*)d_in[8];
    const float* W_node1   = (const float*)d_in[9];
    const float* edge_emb0 = (const float*)d_in[10];
    const float* edge_emb1 = (const float*)d_in[11];
    const float* beta      = (const float*)d_in[12];
    const float* mlp_W     = (const float*)d_in[13];
    const float* mlp_b     = (const float*)d_in[14];
    const float* bn_gamma  = (const float*)d_in[15];
    const float* bn_beta   = (const float*)d_in[16];
    const float* W_out     = (const float*)d_in[17];
    const float* b_out     = (const float*)d_in[18];
    float* out = (float*)d_out;

    char* ws = (char*)d_ws;
    size_t off = 0;
    auto alloc = [&](size_t bytes) -> void* {
        void* p = ws + off;
        off += (bytes + 255) & ~(size_t)255;
        return p;
    };
    float* hv     = (float*)alloc((size_t)N_NODESC * HID * 4);
    float* hv1    = (float*)alloc((size_t)N_NODESC * HID * 4);
    float* xbuf   = (float*)alloc((size_t)N_NODESC * HID * 4);
    float* etab   = (float*)alloc(LAYERS * 18 * HID * 4);
    float* gsums  = (float*)alloc(LAYERS * 2 * HID * 4);  // per-layer gsum+gsumsq
    float* hg     = (float*)alloc((N_GRAPHSC * HID + N_GRAPHSC) * 4);  // sums + counts
    float* cntf   = hg + N_GRAPHSC * HID;
    int* row_ptr  = (int*)alloc((N_NODESC + 1) * 4);
    int* cursor   = (int*)alloc(N_NODESC * 4);
    int* deg      = (int*)alloc(N_NODESC * 4);
    int* part     = (int*)alloc(SCAN_BLK * 4);
    int* bofs     = (int*)alloc(SCAN_BLK * 4);
    int* csr_pack = (int*)alloc((size_t)N_EDGESC * 4);

    // ---- CSR build (edge_dst is layer-invariant) ----
    hipMemsetAsync(deg, 0, N_NODESC * 4, stream);
    k_count<<<(N_EDGESC + 255) / 256, 256, 0, stream>>>(edge_dst, deg);
    k_blocksum<<<SCAN_BLK, 256, 0, stream>>>(deg, part);
    k_scanpart<<<1, 256, 0, stream>>>(part, bofs);
    k_rowptr<<<SCAN_BLK, 256, 0, stream>>>(deg, bofs, row_ptr, cursor);
    k_scatter<<<(N_EDGESC + 255) / 256, 256, 0, stream>>>(
        edge_dst, edge_src, edge_feat0, edge_feat1, cursor, csr_pack);
    k_etab<<<(LAYERS * 18 * HID + 255) / 256, 256, 0, stream>>>(
        edge_emb0, edge_emb1, etab);

    // ---- node embedding ----
    const int NELEM4 = N_NODESC * (HID / 4);
    k_embed<<<(NELEM4 + 255) / 256, 256, 0, stream>>>(
        node_feat0, node_feat1, (const float4*)W_node0, (const float4*)W_node1,
        (float4*)hv);

    // zero all BN accumulators once
    hipMemsetAsync(gsums, 0, LAYERS * 2 * HID * 4, stream);

    // ---- layers ----
    for (int l = 0; l < LAYERS; l++) {
        float* gsum = gsums + l * 2 * HID;
        float* gsumsq = gsum + HID;
        k_bn_stats<<<200, 256, 0, stream>>>(hv, gsum, gsumsq);
        k_hv1<<<(NELEM4 + 255) / 256, 256, 0, stream>>>(
            (const float4*)hv, gsum, gsumsq, bn_gamma + l * HID,
            bn_beta + l * HID, (float4*)hv1);
        k_agg<<<(N_NODESC + 3) / 4, 256, 0, stream>>>(
            hv1, row_ptr, csr_pack, etab + (size_t)l * 18 * HID, beta + l, xbuf);
        dim3 ggrid((N_NODESC + 31) / 32, 2);
        k_gemm<<<ggrid, 256, 0, stream>>>(xbuf, mlp_W + (size_t)l * HID * HID,
                                          mlp_b + l * HID, hv);
    }

    // ---- pooling + output ----
    hipMemsetAsync(hg, 0, (N_GRAPHSC * HID + N_GRAPHSC) * 4, stream);
    k_pool<<<(N_NODESC + 511) / 512, 256, 0, stream>>>(hv, graph_ids, hg, cntf);
    k_out<<<1, 256, 0, stream>>>(hg, cntf, W_out, b_out, out);
}

// Round 4
// 634.624 us; speedup vs baseline: 2.6049x; 1.2436x over previous
//
#include <hip/hip_runtime.h>

#define N_NODESC 50000
#define N_EDGESC 600000
#define HID 128
#define LAYERS 3
#define N_GRAPHSC 16
#define OUT_DIM 14
#define GEN_EPS 1e-7f
#define BN_EPS 1e-5f
#define SCAN_BLK 196     // ceil(50000/256)
#define BN_BLK 250       // stats stage-1 blocks (200 rows each)
#define POOL_BLK 400     // pool stage-1 blocks (125 rows each; 3125%125==0)

// ---------------- CSR build ----------------
__global__ void k_count(const int* __restrict__ dst, int* __restrict__ deg) {
    int i = blockIdx.x * blockDim.x + threadIdx.x;
    if (i < N_EDGESC) atomicAdd(&deg[dst[i]], 1);
}

__global__ void k_blocksum(const int* __restrict__ deg, int* __restrict__ part) {
    __shared__ int sh[256];
    int t = threadIdx.x;
    int i = blockIdx.x * 256 + t;
    sh[t] = (i < N_NODESC) ? deg[i] : 0;
    __syncthreads();
    for (int off = 128; off > 0; off >>= 1) {
        if (t < off) sh[t] += sh[t + off];
        __syncthreads();
    }
    if (t == 0) part[blockIdx.x] = sh[0];
}

__global__ void k_scanpart(const int* __restrict__ part, int* __restrict__ bofs) {
    __shared__ int sh[256];
    int t = threadIdx.x;
    int v = (t < SCAN_BLK) ? part[t] : 0;
    sh[t] = v;
    __syncthreads();
    for (int off = 1; off < 256; off <<= 1) {
        int add = (t >= off) ? sh[t - off] : 0;
        __syncthreads();
        sh[t] += add;
        __syncthreads();
    }
    if (t < SCAN_BLK) bofs[t] = sh[t] - v;  // exclusive
}

__global__ void k_rowptr(const int* __restrict__ deg, const int* __restrict__ bofs,
                         int* __restrict__ row_ptr, int* __restrict__ cursor) {
    __shared__ int sh[256];
    int t = threadIdx.x;
    int i = blockIdx.x * 256 + t;
    int d = (i < N_NODESC) ? deg[i] : 0;
    sh[t] = d;
    __syncthreads();
    for (int off = 1; off < 256; off <<= 1) {
        int add = (t >= off) ? sh[t - off] : 0;
        __syncthreads();
        sh[t] += add;
        __syncthreads();
    }
    if (i < N_NODESC) {
        int rp = bofs[blockIdx.x] + sh[t] - d;
        row_ptr[i] = rp;
        cursor[i] = rp;
    }
    if (i == 0) row_ptr[N_NODESC] = N_EDGESC;
}

__global__ void k_scatter(const int* __restrict__ dst, const int* __restrict__ src,
                          const int* __restrict__ f0, const int* __restrict__ f1,
                          int* __restrict__ cursor, int* __restrict__ csr_pack) {
    int i = blockIdx.x * blockDim.x + threadIdx.x;
    if (i < N_EDGESC) {
        int pos = atomicAdd(&cursor[dst[i]], 1);
        csr_pack[pos] = src[i] | ((f0[i] * 3 + f1[i]) << 20);
    }
}

// ---------------- node embedding ----------------
__global__ void k_embed(const int* __restrict__ f0, const int* __restrict__ f1,
                        const float4* __restrict__ W0, const float4* __restrict__ W1,
                        float4* __restrict__ hv4) {
    int i = blockIdx.x * blockDim.x + threadIdx.x;
    if (i >= N_NODESC * (HID / 4)) return;
    int v = i >> 5, c4 = i & 31;
    float4 a = W0[f0[v] * 32 + c4];
    float4 b = W1[f1[v] * 32 + c4];
    hv4[i] = make_float4(a.x + b.x, a.y + b.y, a.z + b.z, a.w + b.w);
}

// ---------------- BatchNorm stats: 2-stage, branch-free, no atomics ----------
// stage 1: 250 blocks x 200 rows -> bnpart[b][256] (sum||sumsq)
__global__ void k_bn_part(const float* __restrict__ hv, float* __restrict__ bnpart) {
    int tid = threadIdx.x;
    int c = tid & 127, rh = tid >> 7;
    int start = blockIdx.x * 200;
    float s = 0.f, s2 = 0.f;
    for (int r = start + rh; r < start + 200; r += 2) {
        float v = hv[(size_t)r * HID + c];
        s += v; s2 += v * v;
    }
    __shared__ float sh[512];
    sh[tid] = s;
    sh[256 + tid] = s2;
    __syncthreads();
    if (rh == 0) {
        bnpart[blockIdx.x * 256 + c] = s + sh[tid + 128];
        bnpart[blockIdx.x * 256 + 128 + c] = sh[256 + tid] + sh[256 + tid + 128];
    }
}

// stage 2: one block sums 250 partials, computes scale/shift directly
__global__ void k_bn_reduce(const float* __restrict__ bnpart,
                            const float* __restrict__ gamma, const float* __restrict__ betab,
                            float* __restrict__ scale, float* __restrict__ shift) {
    int t = threadIdx.x;
    float tot = 0.f;
    for (int b = 0; b < BN_BLK; b++) tot += bnpart[b * 256 + t];
    __shared__ float sh[256];
    sh[t] = tot;
    __syncthreads();
    if (t < 128) {
        const float invN = 1.f / (float)N_NODESC;
        float mu = sh[t] * invN;
        float var = sh[128 + t] * invN - mu * mu;
        float sc = gamma[t] * rsqrtf(var + BN_EPS);
        scale[t] = sc;
        shift[t] = betab[t] - mu * sc;
    }
}

// ---------------- GENConv aggregation (BN+ReLU fused, pack broadcast) --------
// x[v] = bnrelu(hv[v]) + softmax-agg over incoming edges of
//        m = relu(bnrelu(hv[src]) + etab[f01]) + eps
__global__ __launch_bounds__(256) void k_agg(
    const float* __restrict__ hv, const float* __restrict__ scale,
    const float* __restrict__ shift, const int* __restrict__ row_ptr,
    const int* __restrict__ csr_pack, const float* __restrict__ e0,
    const float* __restrict__ e1, const float* __restrict__ beta_p,
    float* __restrict__ x) {
    __shared__ float2 sh_et[18 * 64];   // [f01][lane] -> channels (2*lane, 2*lane+1)
    int tid = threadIdx.x;
    for (int i = tid; i < 18 * 64; i += 256) {
        int f = i >> 6, ln = i & 63;
        int a = f / 3, b = f - 3 * a;
        float2 ea = *(const float2*)(e0 + a * HID + 2 * ln);
        float2 eb = *(const float2*)(e1 + b * HID + 2 * ln);
        sh_et[i] = make_float2(ea.x + eb.x, ea.y + eb.y);
    }
    int wave = tid >> 6, lane = tid & 63;
    int v = blockIdx.x * 4 + wave;
    int c = lane * 2;
    float beta = *beta_p;
    float sc0 = scale[c], sc1 = scale[c + 1];
    float sf0 = shift[c], sf1 = shift[c + 1];
    __syncthreads();
    if (v >= N_NODESC) return;
    float2 h = *(const float2*)(hv + (size_t)v * HID + c);
    float h10 = fmaxf(fmaf(h.x, sc0, sf0), 0.f);
    float h11 = fmaxf(fmaf(h.y, sc1, sf1), 0.f);
    int p0 = row_ptr[v], p1 = row_ptr[v + 1];
    int deg = p1 - p0;
    float n0 = 0.f, n1 = 0.f, d0 = 0.f, d1 = 0.f;

#define AGG_BODY(J)                                                         \
    {                                                                       \
        int pack = __shfl(pk, (J), 64);                                     \
        int src = pack & 0xFFFFF;                                           \
        int f01 = pack >> 20;                                               \
        float2 hs = *(const float2*)(hv + (size_t)src * HID + c);           \
        float2 t = sh_et[f01 * 64 + lane];                                  \
        float a0 = fmaxf(fmaf(hs.x, sc0, sf0), 0.f);                        \
        float a1 = fmaxf(fmaf(hs.y, sc1, sf1), 0.f);                        \
        float m0 = fmaxf(a0 + t.x, 0.f) + GEN_EPS;                          \
        float m1 = fmaxf(a1 + t.y, 0.f) + GEN_EPS;                          \
        float w0 = __expf(beta * m0);                                       \
        float w1 = __expf(beta * m1);                                       \
        d0 += w0; d1 += w1;                                                 \
        n0 = fmaf(m0, w0, n0); n1 = fmaf(m1, w1, n1);                       \
    }

    for (int base = 0; base < deg; base += 64) {
        int idx = base + lane;
        int pk = (idx < deg) ? csr_pack[p0 + idx] : 0;
        int jn = min(64, deg - base);
        int j = 0;
        for (; j + 2 <= jn; j += 2) {
            AGG_BODY(j)
            AGG_BODY(j + 1)
        }
        if (j < jn) AGG_BODY(j)
    }
#undef AGG_BODY

    float2 o;
    o.x = h10 + (deg ? n0 / d0 : 0.f);
    o.y = h11 + (deg ? n1 / d1 : 0.f);
    *(float2*)(x + (size_t)v * HID + c) = o;
}

// ---------------- MLP GEMM + bias + skip (in-place into hv) ----------------
__global__ __launch_bounds__(256) void k_gemm(const float* __restrict__ x,
                                              const float* __restrict__ W,
                                              const float* __restrict__ b,
                                              float* __restrict__ hv) {
    __shared__ float Ws[HID * 64];       // [k][c], stride 64
    __shared__ float xsT[HID * 34];      // [k][r], stride 34 (2-way alias = free)
    int tid = threadIdx.x;
    int v0 = blockIdx.x * 32;
    int cb = blockIdx.y * 64;
    for (int i = tid; i < HID * 64; i += 256) {
        int k = i >> 6, c = i & 63;
        Ws[i] = W[k * HID + cb + c];
    }
    for (int i = tid; i < 32 * HID; i += 256) {
        int r = i >> 7, k = i & 127;
        int v = v0 + r;
        xsT[k * 34 + r] = (v < N_NODESC) ? x[(size_t)v * HID + k] : 0.f;
    }
    __syncthreads();
    int tx = tid & 15, ty = tid >> 4;
    int c0 = tx * 4, r0 = ty * 2;
    float acc[2][4];
#pragma unroll
    for (int i = 0; i < 2; i++)
#pragma unroll
        for (int j = 0; j < 4; j++) acc[i][j] = 0.f;
    for (int k = 0; k < HID; k++) {
        float4 wv = *(const float4*)&Ws[k * 64 + c0];
        float2 xv = *(const float2*)&xsT[k * 34 + r0];
        acc[0][0] = fmaf(xv.x, wv.x, acc[0][0]);
        acc[0][1] = fmaf(xv.x, wv.y, acc[0][1]);
        acc[0][2] = fmaf(xv.x, wv.z, acc[0][2]);
        acc[0][3] = fmaf(xv.x, wv.w, acc[0][3]);
        acc[1][0] = fmaf(xv.y, wv.x, acc[1][0]);
        acc[1][1] = fmaf(xv.y, wv.y, acc[1][1]);
        acc[1][2] = fmaf(xv.y, wv.z, acc[1][2]);
        acc[1][3] = fmaf(xv.y, wv.w, acc[1][3]);
    }
#pragma unroll
    for (int i = 0; i < 2; i++) {
        int v = v0 + r0 + i;
        if (v < N_NODESC) {
#pragma unroll
            for (int j = 0; j < 4; j++) {
                int c = cb + c0 + j;
                size_t idx = (size_t)v * HID + c;
                hv[idx] = acc[i][j] + b[c] + hv[idx];
            }
        }
    }
}

// ---------------- pooling: 2-stage, branch-free, no atomics ----------------
// stage 1: 400 blocks x 125 rows (each block entirely within one graph)
__global__ void k_pool(const float* __restrict__ hv, float* __restrict__ part2) {
    int tid = threadIdx.x;
    int c = tid & 127, rh = tid >> 7;
    int start = blockIdx.x * 125;
    float acc = 0.f;
    for (int r = start + rh; r < start + 125; r += 2)
        acc += hv[(size_t)r * HID + c];
    __shared__ float sh[256];
    sh[tid] = acc;
    __syncthreads();
    if (rh == 0) part2[blockIdx.x * 128 + c] = acc + sh[tid + 128];
}

// stage 2: 8 blocks x 256 threads; thread (g,c) sums 25 partials
__global__ void k_poolred(const float* __restrict__ part2, float* __restrict__ hg) {
    int t = blockIdx.x * 256 + threadIdx.x;   // t = g*128 + c
    int g = t >> 7, c = t & 127;
    float s = 0.f;
#pragma unroll
    for (int i = 0; i < 25; i++) s += part2[(g * 25 + i) * 128 + c];
    hg[t] = s;
}

__global__ void k_out(const float* __restrict__ hg, const float* __restrict__ Wo,
                      const float* __restrict__ bo, float* __restrict__ out) {
    int tid = threadIdx.x;
    if (tid >= N_GRAPHSC * OUT_DIM) return;
    int g = tid / OUT_DIM, o = tid % OUT_DIM;
    const float inv = (float)N_GRAPHSC / (float)N_NODESC;  // 1/3125
    float acc = bo[o];
    for (int k = 0; k < HID; k++)
        acc += hg[g * HID + k] * inv * Wo[k * OUT_DIM + o];
    out[tid] = acc;
}

extern "C" void kernel_launch(void* const* d_in, const int* in_sizes, int n_in,
                              void* d_out, int out_size, void* d_ws, size_t ws_size,
                              hipStream_t stream) {
    const int* node_feat0 = (const int*)d_in[0];
    const int* node_feat1 = (const int*)d_in[1];
    const int* edge_feat0 = (const int*)d_in[2];
    const int* edge_feat1 = (const int*)d_in[3];
    const int* edge_src   = (const int*)d_in[4];
    const int* edge_dst   = (const int*)d_in[5];
    const float* W_node0   = (const float*)d_in[8];
    const float* W_node1   = (const float*)d_in[9];
    const float* edge_emb0 = (const float*)d_in[10];
    const float* edge_emb1 = (const float*)d_in[11];
    const float* beta      = (const float*)d_in[12];
    const float* mlp_W     = (const float*)d_in[13];
    const float* mlp_b     = (const float*)d_in[14];
    const float* bn_gamma  = (const float*)d_in[15];
    const float* bn_beta   = (const float*)d_in[16];
    const float* W_out     = (const float*)d_in[17];
    const float* b_out     = (const float*)d_in[18];
    float* out = (float*)d_out;

    char* ws = (char*)d_ws;
    size_t off = 0;
    auto alloc = [&](size_t bytes) -> void* {
        void* p = ws + off;
        off += (bytes + 255) & ~(size_t)255;
        return p;
    };
    float* hv     = (float*)alloc((size_t)N_NODESC * HID * 4);
    float* xbuf   = (float*)alloc((size_t)N_NODESC * HID * 4);
    float* bnpart = (float*)alloc(BN_BLK * 256 * 4);
    float* scale  = (float*)alloc(HID * 4);
    float* shift  = (float*)alloc(HID * 4);
    float* part2  = (float*)alloc(POOL_BLK * 128 * 4);
    float* hg     = (float*)alloc(N_GRAPHSC * HID * 4);
    int* row_ptr  = (int*)alloc((N_NODESC + 1) * 4);
    int* cursor   = (int*)alloc(N_NODESC * 4);
    int* deg      = (int*)alloc(N_NODESC * 4);
    int* part     = (int*)alloc(SCAN_BLK * 4);
    int* bofs     = (int*)alloc(SCAN_BLK * 4);
    int* csr_pack = (int*)alloc((size_t)N_EDGESC * 4);

    // ---- CSR build (edge_dst is layer-invariant) ----
    hipMemsetAsync(deg, 0, N_NODESC * 4, stream);
    k_count<<<(N_EDGESC + 255) / 256, 256, 0, stream>>>(edge_dst, deg);
    k_blocksum<<<SCAN_BLK, 256, 0, stream>>>(deg, part);
    k_scanpart<<<1, 256, 0, stream>>>(part, bofs);
    k_rowptr<<<SCAN_BLK, 256, 0, stream>>>(deg, bofs, row_ptr, cursor);
    k_scatter<<<(N_EDGESC + 255) / 256, 256, 0, stream>>>(
        edge_dst, edge_src, edge_feat0, edge_feat1, cursor, csr_pack);

    // ---- node embedding ----
    const int NELEM4 = N_NODESC * (HID / 4);
    k_embed<<<(NELEM4 + 255) / 256, 256, 0, stream>>>(
        node_feat0, node_feat1, (const float4*)W_node0, (const float4*)W_node1,
        (float4*)hv);

    // ---- layers ----
    for (int l = 0; l < LAYERS; l++) {
        k_bn_part<<<BN_BLK, 256, 0, stream>>>(hv, bnpart);
        k_bn_reduce<<<1, 256, 0, stream>>>(bnpart, bn_gamma + l * HID,
                                           bn_beta + l * HID, scale, shift);
        k_agg<<<(N_NODESC + 3) / 4, 256, 0, stream>>>(
            hv, scale, shift, row_ptr, csr_pack,
            edge_emb0 + (size_t)l * 6 * HID, edge_emb1 + (size_t)l * 3 * HID,
            beta + l, xbuf);
        dim3 ggrid((N_NODESC + 31) / 32, 2);
        k_gemm<<<ggrid, 256, 0, stream>>>(xbuf, mlp_W + (size_t)l * HID * HID,
                                          mlp_b + l * HID, hv);
    }

    // ---- pooling + output ----
    k_pool<<<POOL_BLK, 256, 0, stream>>>(hv, part2);
    k_poolred<<<8, 256, 0, stream>>>(part2, hg);
    k_out<<<1, 256, 0, stream>>>(hg, W_out, b_out, out);
}

// Round 5
// 461.731 us; speedup vs baseline: 3.5803x; 1.3744x over previous
//
#include <hip/hip_runtime.h>

#define N_NODESC 50000
#define N_EDGESC 600000
#define HID 128
#define LAYERS 3
#define N_GRAPHSC 16
#define OUT_DIM 14
#define GEN_EPS 1e-7f
#define BN_EPS 1e-5f
#define SCAN_BLK 196     // ceil(50000/256)
#define POOL_BLK 400     // pool stage-1 blocks (125 rows each)
#define EMB_BLK 6250     // embed blocks (8 rows each)
#define GEMM_BLK 782     // ceil(50000/64)
#define XPAD 50048       // x rows padded to GEMM_BLK*64

typedef short bf16x8 __attribute__((ext_vector_type(8)));
typedef float f32x4 __attribute__((ext_vector_type(4)));

__device__ __forceinline__ unsigned short f2bf(float f) {
    union { float f; unsigned u; } v; v.f = f;
    unsigned r = v.u + 0x7FFF + ((v.u >> 16) & 1);  // RNE
    return (unsigned short)(r >> 16);
}
__device__ __forceinline__ float bf_lo(unsigned u) {
    return __uint_as_float(u << 16);
}
__device__ __forceinline__ float bf_hi(unsigned u) {
    return __uint_as_float(u & 0xFFFF0000u);
}

// ---------------- CSR build ----------------
__global__ void k_count(const int* __restrict__ dst, int* __restrict__ deg) {
    int i = blockIdx.x * blockDim.x + threadIdx.x;
    if (i < N_EDGESC) atomicAdd(&deg[dst[i]], 1);
}

__global__ void k_blocksum(const int* __restrict__ deg, int* __restrict__ part) {
    __shared__ int sh[256];
    int t = threadIdx.x;
    int i = blockIdx.x * 256 + t;
    sh[t] = (i < N_NODESC) ? deg[i] : 0;
    __syncthreads();
    for (int off = 128; off > 0; off >>= 1) {
        if (t < off) sh[t] += sh[t + off];
        __syncthreads();
    }
    if (t == 0) part[blockIdx.x] = sh[0];
}

__global__ void k_scanpart(const int* __restrict__ part, int* __restrict__ bofs) {
    __shared__ int sh[256];
    int t = threadIdx.x;
    int v = (t < SCAN_BLK) ? part[t] : 0;
    sh[t] = v;
    __syncthreads();
    for (int off = 1; off < 256; off <<= 1) {
        int add = (t >= off) ? sh[t - off] : 0;
        __syncthreads();
        sh[t] += add;
        __syncthreads();
    }
    if (t < SCAN_BLK) bofs[t] = sh[t] - v;  // exclusive
}

__global__ void k_rowptr(const int* __restrict__ deg, const int* __restrict__ bofs,
                         int* __restrict__ row_ptr, int* __restrict__ cursor) {
    __shared__ int sh[256];
    int t = threadIdx.x;
    int i = blockIdx.x * 256 + t;
    int d = (i < N_NODESC) ? deg[i] : 0;
    sh[t] = d;
    __syncthreads();
    for (int off = 1; off < 256; off <<= 1) {
        int add = (t >= off) ? sh[t - off] : 0;
        __syncthreads();
        sh[t] += add;
        __syncthreads();
    }
    if (i < N_NODESC) {
        int rp = bofs[blockIdx.x] + sh[t] - d;
        row_ptr[i] = rp;
        cursor[i] = rp;
    }
    if (i == 0) row_ptr[N_NODESC] = N_EDGESC;
}

__global__ void k_scatter(const int* __restrict__ dst, const int* __restrict__ src,
                          const int* __restrict__ f0, const int* __restrict__ f1,
                          int* __restrict__ cursor, int* __restrict__ csr_pack) {
    int i = blockIdx.x * blockDim.x + threadIdx.x;
    if (i < N_EDGESC) {
        int pos = atomicAdd(&cursor[dst[i]], 1);
        csr_pack[pos] = src[i] | ((f0[i] * 3 + f1[i]) << 20);
    }
}

// W -> bf16 in MFMA B-fragment order: wf[l][ks][nt][lane][j] =
//   bf16(W[l][ks*32 + (lane>>4)*8 + j][nt*16 + (lane&15)])
__global__ void k_wfrag(const float* __restrict__ W, unsigned short* __restrict__ wf) {
    int i = blockIdx.x * blockDim.x + threadIdx.x;
    if (i >= LAYERS * 4 * 8 * 64 * 8) return;
    int j = i & 7;
    int lane = (i >> 3) & 63;
    int nt = (i >> 9) & 7;
    int ks = (i >> 12) & 3;
    int l = i >> 14;
    int k = ks * 32 + (lane >> 4) * 8 + j;
    int n = nt * 16 + (lane & 15);
    wf[i] = f2bf(W[(size_t)l * HID * HID + k * HID + n]);
}

// ---------------- node embedding (+ BN partials for layer 0) ----------------
__global__ void k_embed(const int* __restrict__ f0, const int* __restrict__ f1,
                        const float4* __restrict__ W0, const float4* __restrict__ W1,
                        float4* __restrict__ hv4, float* __restrict__ part) {
    __shared__ float sh[1024], sh2[1024];
    int tid = threadIdx.x;
    int i = blockIdx.x * 256 + tid;
    int v = i >> 5, c4 = i & 31;
    float4 a = W0[f0[v] * 32 + c4];
    float4 b = W1[f1[v] * 32 + c4];
    float4 o = make_float4(a.x + b.x, a.y + b.y, a.z + b.z, a.w + b.w);
    hv4[i] = o;
    sh[tid * 4 + 0] = o.x; sh2[tid * 4 + 0] = o.x * o.x;
    sh[tid * 4 + 1] = o.y; sh2[tid * 4 + 1] = o.y * o.y;
    sh[tid * 4 + 2] = o.z; sh2[tid * 4 + 2] = o.z * o.z;
    sh[tid * 4 + 3] = o.w; sh2[tid * 4 + 3] = o.w * o.w;
    __syncthreads();
    if (tid < 128) {
        int c4i = tid >> 2, j = tid & 3;   // channel = c4i*4 + j = tid
        float s = 0.f, s2 = 0.f;
#pragma unroll
        for (int r = 0; r < 8; r++) {
            s += sh[(r * 32 + c4i) * 4 + j];
            s2 += sh2[(r * 32 + c4i) * 4 + j];
        }
        part[(size_t)blockIdx.x * 256 + tid] = s;
        part[(size_t)blockIdx.x * 256 + 128 + tid] = s2;
    }
}

// sum nparts partials -> gsum[256] (sum||sumsq); one block per slot
__global__ void k_bn_reduce2(const float* __restrict__ part, int nparts,
                             float* __restrict__ gsum) {
    int slot = blockIdx.x;
    int t = threadIdx.x;
    float s = 0.f;
    for (int p = t; p < nparts; p += 256) s += part[(size_t)p * 256 + slot];
    __shared__ float sh[256];
    sh[t] = s;
    __syncthreads();
    for (int o = 128; o > 0; o >>= 1) {
        if (t < o) sh[t] += sh[t + o];
        __syncthreads();
    }
    if (t == 0) gsum[slot] = sh[0];
}

// BN+ReLU -> bf16 pair-packed hv1 (scale/shift computed inline from stats)
__global__ void k_hv1b(const float2* __restrict__ hv2, const float* __restrict__ gsum,
                       const float* __restrict__ gamma, const float* __restrict__ betab,
                       unsigned* __restrict__ hv1b) {
    int i = blockIdx.x * 256 + threadIdx.x;   // < 50000*64
    int c = (i & 63) * 2;
    const float invN = 1.f / (float)N_NODESC;
    float2 h = hv2[i];
    float mu0 = gsum[c] * invN, mu1 = gsum[c + 1] * invN;
    float var0 = gsum[128 + c] * invN - mu0 * mu0;
    float var1 = gsum[129 + c] * invN - mu1 * mu1;
    float sc0 = gamma[c] * rsqrtf(var0 + BN_EPS);
    float sc1 = gamma[c + 1] * rsqrtf(var1 + BN_EPS);
    float sf0 = betab[c] - mu0 * sc0;
    float sf1 = betab[c + 1] - mu1 * sc1;
    float a0 = fmaxf(fmaf(h.x, sc0, sf0), 0.f);
    float a1 = fmaxf(fmaf(h.y, sc1, sf1), 0.f);
    hv1b[i] = (unsigned)f2bf(a0) | ((unsigned)f2bf(a1) << 16);
}

// ---------------- GENConv aggregation (bf16 gather, bf16 x out) -------------
__global__ __launch_bounds__(256) void k_agg(
    const unsigned* __restrict__ hv1b, const int* __restrict__ row_ptr,
    const int* __restrict__ csr_pack, const float* __restrict__ e0,
    const float* __restrict__ e1, const float* __restrict__ beta_p,
    unsigned* __restrict__ xb) {
    __shared__ float2 sh_et[18 * 64];   // [f01][lane] -> channels (2*lane, 2*lane+1)
    int tid = threadIdx.x;
    for (int i = tid; i < 18 * 64; i += 256) {
        int f = i >> 6, ln = i & 63;
        int a = f / 3, b = f - 3 * a;
        float2 ea = *(const float2*)(e0 + a * HID + 2 * ln);
        float2 eb = *(const float2*)(e1 + b * HID + 2 * ln);
        sh_et[i] = make_float2(ea.x + eb.x, ea.y + eb.y);
    }
    int wave = tid >> 6, lane = tid & 63;
    int v = blockIdx.x * 4 + wave;
    float beta = *beta_p;
    __syncthreads();
    if (v >= N_NODESC) return;
    unsigned su = hv1b[(size_t)v * 64 + lane];
    float h10 = bf_lo(su), h11 = bf_hi(su);
    int p0 = row_ptr[v], p1 = row_ptr[v + 1];
    int deg = p1 - p0;
    float n0 = 0.f, n1 = 0.f, d0 = 0.f, d1 = 0.f;

#define AGG_BODY(J)                                                         \
    {                                                                       \
        int pack = __shfl(pk, (J), 64);                                     \
        int src = pack & 0xFFFFF;                                           \
        int f01 = pack >> 20;                                               \
        unsigned u = hv1b[(size_t)src * 64 + lane];                         \
        float2 t = sh_et[f01 * 64 + lane];                                  \
        float m0 = fmaxf(bf_lo(u) + t.x, 0.f) + GEN_EPS;                    \
        float m1 = fmaxf(bf_hi(u) + t.y, 0.f) + GEN_EPS;                    \
        float w0 = __expf(beta * m0);                                       \
        float w1 = __expf(beta * m1);                                       \
        d0 += w0; d1 += w1;                                                 \
        n0 = fmaf(m0, w0, n0); n1 = fmaf(m1, w1, n1);                       \
    }

    for (int base = 0; base < deg; base += 64) {
        int idx = base + lane;
        int pk = (idx < deg) ? csr_pack[p0 + idx] : 0;
        int jn = min(64, deg - base);
        int j = 0;
        for (; j + 2 <= jn; j += 2) {
            AGG_BODY(j)
            AGG_BODY(j + 1)
        }
        if (j < jn) AGG_BODY(j)
    }
#undef AGG_BODY

    float ox = h10 + (deg ? n0 / d0 : 0.f);
    float oy = h11 + (deg ? n1 / d1 : 0.f);
    xb[(size_t)v * 64 + lane] = (unsigned)f2bf(ox) | ((unsigned)f2bf(oy) << 16);
}

// ---------------- MFMA GEMM + bias + skip + next-layer BN partials ----------
// hv[v][c] = x[v][:] @ W[:][c] + b[c] + hv[v][c];  part[bid][*] = sum/sumsq
__global__ __launch_bounds__(256) void k_gemm(
    const unsigned short* __restrict__ x,   // [XPAD][128] bf16
    const unsigned short* __restrict__ wf,  // [4][8][64][8] bf16 frags
    const float* __restrict__ b, float* __restrict__ hv,
    float* __restrict__ part) {
    __shared__ float shs[512], shs2[512];
    int tid = threadIdx.x;
    int w = tid >> 6, lane = tid & 63;
    int m0 = blockIdx.x * 64 + w * 16;
    int mrow = lane & 15, grp = lane >> 4;
    // A fragments: rows m0..m0+15, all K
    bf16x8 af[4];
    const unsigned short* xrow = x + (size_t)(m0 + mrow) * HID + grp * 8;
#pragma unroll
    for (int ks = 0; ks < 4; ks++)
        af[ks] = *(const bf16x8*)(xrow + ks * 32);
    f32x4 acc[8];
#pragma unroll
    for (int nt = 0; nt < 8; nt++) acc[nt] = (f32x4){0.f, 0.f, 0.f, 0.f};
#pragma unroll
    for (int nt = 0; nt < 8; nt++) {
#pragma unroll
        for (int ks = 0; ks < 4; ks++) {
            bf16x8 bf = *(const bf16x8*)(wf + (size_t)((ks * 8 + nt) * 64 + lane) * 8);
            acc[nt] = __builtin_amdgcn_mfma_f32_16x16x32_bf16(af[ks], bf, acc[nt], 0, 0, 0);
        }
    }
    // epilogue: bias + skip + store + per-column partial stats
#pragma unroll
    for (int nt = 0; nt < 8; nt++) {
        int col = nt * 16 + mrow;
        float bias = b[col];
        float s = 0.f, s2 = 0.f;
#pragma unroll
        for (int r = 0; r < 4; r++) {
            int v = m0 + grp * 4 + r;
            if (v < N_NODESC) {
                size_t idx = (size_t)v * HID + col;
                float o = acc[nt][r] + bias + hv[idx];
                hv[idx] = o;
                s += o; s2 += o * o;
            }
        }
        s  += __shfl_xor(s, 16, 64);  s  += __shfl_xor(s, 32, 64);
        s2 += __shfl_xor(s2, 16, 64); s2 += __shfl_xor(s2, 32, 64);
        if (lane < 16) { shs[w * 128 + col] = s; shs2[w * 128 + col] = s2; }
    }
    __syncthreads();
    if (tid < 128) {
        part[(size_t)blockIdx.x * 256 + tid] =
            shs[tid] + shs[128 + tid] + shs[256 + tid] + shs[384 + tid];
    } else {
        int c = tid - 128;
        part[(size_t)blockIdx.x * 256 + tid] =
            shs2[c] + shs2[128 + c] + shs2[256 + c] + shs2[384 + c];
    }
}

// ---------------- pooling: 2-stage, branch-free, no atomics ----------------
__global__ void k_pool(const float* __restrict__ hv, float* __restrict__ part2) {
    int tid = threadIdx.x;
    int c = tid & 127, rh = tid >> 7;
    int start = blockIdx.x * 125;
    float acc = 0.f;
    for (int r = start + rh; r < start + 125; r += 2)
        acc += hv[(size_t)r * HID + c];
    __shared__ float sh[256];
    sh[tid] = acc;
    __syncthreads();
    if (rh == 0) part2[blockIdx.x * 128 + c] = acc + sh[tid + 128];
}

__global__ void k_poolred(const float* __restrict__ part2, float* __restrict__ hg) {
    int t = blockIdx.x * 256 + threadIdx.x;   // t = g*128 + c
    int g = t >> 7, c = t & 127;
    float s = 0.f;
#pragma unroll
    for (int i = 0; i < 25; i++) s += part2[(g * 25 + i) * 128 + c];
    hg[t] = s;
}

__global__ void k_out(const float* __restrict__ hg, const float* __restrict__ Wo,
                      const float* __restrict__ bo, float* __restrict__ out) {
    int tid = threadIdx.x;
    if (tid >= N_GRAPHSC * OUT_DIM) return;
    int g = tid / OUT_DIM, o = tid % OUT_DIM;
    const float inv = (float)N_GRAPHSC / (float)N_NODESC;
    float acc = bo[o];
    for (int k = 0; k < HID; k++)
        acc += hg[g * HID + k] * inv * Wo[k * OUT_DIM + o];
    out[tid] = acc;
}

extern "C" void kernel_launch(void* const* d_in, const int* in_sizes, int n_in,
                              void* d_out, int out_size, void* d_ws, size_t ws_size,
                              hipStream_t stream) {
    const int* node_feat0 = (const int*)d_in[0];
    const int* node_feat1 = (const int*)d_in[1];
    const int* edge_feat0 = (const int*)d_in[2];
    const int* edge_feat1 = (const int*)d_in[3];
    const int* edge_src   = (const int*)d_in[4];
    const int* edge_dst   = (const int*)d_in[5];
    const float* W_node0   = (const float*)d_in[8];
    const float* W_node1   = (const float*)d_in[9];
    const float* edge_emb0 = (const float*)d_in[10];
    const float* edge_emb1 = (const float*)d_in[11];
    const float* beta      = (const float*)d_in[12];
    const float* mlp_W     = (const float*)d_in[13];
    const float* mlp_b     = (const float*)d_in[14];
    const float* bn_gamma  = (const float*)d_in[15];
    const float* bn_beta   = (const float*)d_in[16];
    const float* W_out     = (const float*)d_in[17];
    const float* b_out     = (const float*)d_in[18];
    float* out = (float*)d_out;

    char* ws = (char*)d_ws;
    size_t off = 0;
    auto alloc = [&](size_t bytes) -> void* {
        void* p = ws + off;
        off += (bytes + 255) & ~(size_t)255;
        return p;
    };
    float* hv      = (float*)alloc((size_t)N_NODESC * HID * 4);
    unsigned* xb   = (unsigned*)alloc((size_t)XPAD * 64 * 4);      // bf16 pairs
    unsigned* hv1b = (unsigned*)alloc((size_t)N_NODESC * 64 * 4);  // bf16 pairs
    float* bnpart  = (float*)alloc((size_t)EMB_BLK * 256 * 4);
    float* gsum    = (float*)alloc(256 * 4);
    unsigned short* wfrag = (unsigned short*)alloc((size_t)LAYERS * 16384 * 2);
    float* part2   = (float*)alloc(POOL_BLK * 128 * 4);
    float* hg      = (float*)alloc(N_GRAPHSC * HID * 4);
    int* row_ptr   = (int*)alloc((N_NODESC + 1) * 4);
    int* cursor    = (int*)alloc(N_NODESC * 4);
    int* deg       = (int*)alloc(N_NODESC * 4);
    int* part      = (int*)alloc(SCAN_BLK * 4);
    int* bofs      = (int*)alloc(SCAN_BLK * 4);
    int* csr_pack  = (int*)alloc((size_t)N_EDGESC * 4);

    // ---- CSR build (edge_dst is layer-invariant) ----
    hipMemsetAsync(deg, 0, N_NODESC * 4, stream);
    k_count<<<(N_EDGESC + 255) / 256, 256, 0, stream>>>(edge_dst, deg);
    k_blocksum<<<SCAN_BLK, 256, 0, stream>>>(deg, part);
    k_scanpart<<<1, 256, 0, stream>>>(part, bofs);
    k_rowptr<<<SCAN_BLK, 256, 0, stream>>>(deg, bofs, row_ptr, cursor);
    k_scatter<<<(N_EDGESC + 255) / 256, 256, 0, stream>>>(
        edge_dst, edge_src, edge_feat0, edge_feat1, cursor, csr_pack);
    k_wfrag<<<(LAYERS * 16384 + 255) / 256, 256, 0, stream>>>(mlp_W, wfrag);

    // ---- node embedding (+ layer-0 BN partials) ----
    k_embed<<<EMB_BLK, 256, 0, stream>>>(
        node_feat0, node_feat1, (const float4*)W_node0, (const float4*)W_node1,
        (float4*)hv, bnpart);

    // ---- layers ----
    for (int l = 0; l < LAYERS; l++) {
        int nparts = (l == 0) ? EMB_BLK : GEMM_BLK;
        k_bn_reduce2<<<256, 256, 0, stream>>>(bnpart, nparts, gsum);
        k_hv1b<<<(N_NODESC * 64) / 256, 256, 0, stream>>>(
            (const float2*)hv, gsum, bn_gamma + l * HID, bn_beta + l * HID, hv1b);
        k_agg<<<(N_NODESC + 3) / 4, 256, 0, stream>>>(
            hv1b, row_ptr, csr_pack,
            edge_emb0 + (size_t)l * 6 * HID, edge_emb1 + (size_t)l * 3 * HID,
            beta + l, xb);
        k_gemm<<<GEMM_BLK, 256, 0, stream>>>(
            (const unsigned short*)xb, wfrag + (size_t)l * 16384,
            mlp_b + l * HID, hv, bnpart);
    }

    // ---- pooling + output ----
    k_pool<<<POOL_BLK, 256, 0, stream>>>(hv, part2);
    k_poolred<<<8, 256, 0, stream>>>(part2, hg);
    k_out<<<1, 256, 0, stream>>>(hg, W_out, b_out, out);
}